// Round 6
// baseline (957.305 us; speedup 1.0000x reference)
//
#include <hip/hip_runtime.h>
#include <math.h>

#define B_ 32
#define T_ 128
#define D_ 768
#define A_ 512
#define R_ 128
#define L_ 50

// ---------------------------------------------------------------------------
// Fused projection GEMM: HA/DA/HL/DL = ELU(X @ W + b) in one launch.
// ---------------------------------------------------------------------------
__global__ __launch_bounds__(256)
void proj_gemm_k(const float* __restrict__ X,
                 const float* __restrict__ Wha, const float* __restrict__ bha,
                 const float* __restrict__ Wda, const float* __restrict__ bda,
                 const float* __restrict__ Whl, const float* __restrict__ bhl,
                 const float* __restrict__ Wdl, const float* __restrict__ bdl,
                 float* __restrict__ HA, float* __restrict__ DA,
                 float* __restrict__ HL, float* __restrict__ DL)
{
    __shared__ float As[16][68];
    __shared__ float Bs[16][132];
    const int bx = blockIdx.x;
    const float *W, *bias; float* C; int ld, ncol;
    if (bx < 4)      { W = Wha; bias = bha; C = HA; ld = 512; ncol = bx * 128; }
    else if (bx < 8) { W = Wda; bias = bda; C = DA; ld = 512; ncol = (bx - 4) * 128; }
    else if (bx == 8){ W = Whl; bias = bhl; C = HL; ld = 128; ncol = 0; }
    else             { W = Wdl; bias = bdl; C = DL; ld = 128; ncol = 0; }
    const int m0 = blockIdx.y * 64;
    const int tid = threadIdx.x;
    const int tx = tid & 15, ry = tid >> 4;
    float acc[4][8] = {};
    for (int k0 = 0; k0 < 768; k0 += 16) {
        {
            int row = tid >> 2, kb = (tid & 3) * 4;
            float4 a = *(const float4*)&X[(size_t)(m0 + row) * 768 + k0 + kb];
            As[kb + 0][row] = a.x; As[kb + 1][row] = a.y;
            As[kb + 2][row] = a.z; As[kb + 3][row] = a.w;
        }
        {
            int kk = tid >> 4, c0 = (tid & 15) * 4;
            const float* Bp = &W[(size_t)(k0 + kk) * ld + ncol + c0];
            *(float4*)&Bs[kk][c0] = *(const float4*)&Bp[0];
            *(float4*)&Bs[kk][c0 + 64] = *(const float4*)&Bp[64];
        }
        __syncthreads();
#pragma unroll
        for (int kk = 0; kk < 16; ++kk) {
            float4 a4 = *(const float4*)&As[kk][ry * 4];
            float4 b0 = *(const float4*)&Bs[kk][tx * 4];
            float4 b1 = *(const float4*)&Bs[kk][tx * 4 + 64];
            float av[4] = { a4.x, a4.y, a4.z, a4.w };
            float bv[8] = { b0.x, b0.y, b0.z, b0.w, b1.x, b1.y, b1.z, b1.w };
#pragma unroll
            for (int i = 0; i < 4; ++i)
#pragma unroll
                for (int j = 0; j < 8; ++j)
                    acc[i][j] += av[i] * bv[j];
        }
        __syncthreads();
    }
    float bv0[8];
    {
        float4 q0 = *(const float4*)&bias[ncol + tx * 4];
        float4 q1 = *(const float4*)&bias[ncol + tx * 4 + 64];
        bv0[0] = q0.x; bv0[1] = q0.y; bv0[2] = q0.z; bv0[3] = q0.w;
        bv0[4] = q1.x; bv0[5] = q1.y; bv0[6] = q1.z; bv0[7] = q1.w;
    }
#pragma unroll
    for (int i = 0; i < 4; ++i) {
        int m = m0 + ry * 4 + i;
        size_t base = (size_t)m * ld + ncol;
        float o[8];
#pragma unroll
        for (int j = 0; j < 8; ++j) {
            float v = acc[i][j] + bv0[j];
            o[j] = v > 0.0f ? v : expm1f(v);
        }
        float4 s0 = { o[0], o[1], o[2], o[3] };
        float4 s1 = { o[4], o[5], o[6], o[7] };
        *(float4*)&C[base + tx * 4] = s0;
        *(float4*)&C[base + tx * 4 + 64] = s1;
    }
}

// ---------------------------------------------------------------------------
// fp32 GEMM, tile 64x128, 256 threads, 4x8 acc/thread, b128 LDS reads.
// ---------------------------------------------------------------------------
__global__ __launch_bounds__(256)
void gemm_k(const float* __restrict__ A, const float* __restrict__ B,
            const float* __restrict__ bias, float* __restrict__ C,
            int K, int lda, int ldb, int ldc,
            long long sA, long long sB, long long sC, long long c_outer, int flags)
{
    __shared__ float As[16][68];
    __shared__ float Bs[16][132];
    A += (size_t)blockIdx.z * sA;
    B += (size_t)blockIdx.z * sB;
    C += (size_t)blockIdx.z * sC;
    const int m0 = blockIdx.y * 64, n0 = blockIdx.x * 128;
    const int tid = threadIdx.x;
    const int tx = tid & 15, ry = tid >> 4;
    float acc[4][8] = {};
    for (int k0 = 0; k0 < K; k0 += 16) {
        {
            int row = tid >> 2, kb = (tid & 3) * 4;
            float4 a = *(const float4*)&A[(size_t)(m0 + row) * lda + k0 + kb];
            As[kb + 0][row] = a.x; As[kb + 1][row] = a.y;
            As[kb + 2][row] = a.z; As[kb + 3][row] = a.w;
        }
        if (!(flags & 4)) {
            int kk = tid >> 4, c0 = (tid & 15) * 4;
            const float* Bp = &B[(size_t)(k0 + kk) * ldb + n0 + c0];
            *(float4*)&Bs[kk][c0] = *(const float4*)&Bp[0];
            *(float4*)&Bs[kk][c0 + 64] = *(const float4*)&Bp[64];
        } else {
            int col = tid >> 1, kb = (tid & 1) * 8;
            const float* Bp = &B[(size_t)(n0 + col) * ldb + k0 + kb];
            float4 b0 = *(const float4*)&Bp[0];
            float4 b1 = *(const float4*)&Bp[4];
            Bs[kb + 0][col] = b0.x; Bs[kb + 1][col] = b0.y;
            Bs[kb + 2][col] = b0.z; Bs[kb + 3][col] = b0.w;
            Bs[kb + 4][col] = b1.x; Bs[kb + 5][col] = b1.y;
            Bs[kb + 6][col] = b1.z; Bs[kb + 7][col] = b1.w;
        }
        __syncthreads();
#pragma unroll
        for (int kk = 0; kk < 16; ++kk) {
            float4 a4 = *(const float4*)&As[kk][ry * 4];
            float4 b0 = *(const float4*)&Bs[kk][tx * 4];
            float4 b1 = *(const float4*)&Bs[kk][tx * 4 + 64];
            float av[4] = { a4.x, a4.y, a4.z, a4.w };
            float bv[8] = { b0.x, b0.y, b0.z, b0.w, b1.x, b1.y, b1.z, b1.w };
#pragma unroll
            for (int i = 0; i < 4; ++i)
#pragma unroll
                for (int j = 0; j < 8; ++j)
                    acc[i][j] += av[i] * bv[j];
        }
        __syncthreads();
    }
    float bv0[8] = {};
    if (flags & 1) {
        float4 q0 = *(const float4*)&bias[n0 + tx * 4];
        float4 q1 = *(const float4*)&bias[n0 + tx * 4 + 64];
        bv0[0] = q0.x; bv0[1] = q0.y; bv0[2] = q0.z; bv0[3] = q0.w;
        bv0[4] = q1.x; bv0[5] = q1.y; bv0[6] = q1.z; bv0[7] = q1.w;
    }
#pragma unroll
    for (int i = 0; i < 4; ++i) {
        int m = m0 + ry * 4 + i;
        size_t base = (size_t)(m >> 7) * c_outer + (size_t)(m & 127) * ldc + n0;
        float o[8];
#pragma unroll
        for (int j = 0; j < 8; ++j) {
            float v = acc[i][j] + bv0[j];
            if (flags & 2) v = v > 0.0f ? v : expm1f(v);
            o[j] = v;
        }
        float4 s0 = { o[0], o[1], o[2], o[3] };
        float4 s1 = { o[4], o[5], o[6], o[7] };
        *(float4*)&C[base + tx * 4] = s0;
        *(float4*)&C[base + tx * 4 + 64] = s1;
    }
}

// 128x128 per-batch transpose: DLt[b][s][j] = DL[b][j][s]
__global__ __launch_bounds__(256)
void transpose_k(const float* __restrict__ in, float* __restrict__ out)
{
    __shared__ float tile[32][33];
    int b = blockIdx.z;
    int bx = blockIdx.x, by = blockIdx.y;
    int tx = threadIdx.x, ty = threadIdx.y; // (32,8)
    const float* src = in + (size_t)b * T_ * R_;
    float* dst = out + (size_t)b * T_ * R_;
#pragma unroll
    for (int r = 0; r < 4; ++r)
        tile[ty + 8 * r][tx] = src[(size_t)(by * 32 + ty + 8 * r) * 128 + bx * 32 + tx];
    __syncthreads();
#pragma unroll
    for (int r = 0; r < 4; ++r)
        dst[(size_t)(bx * 32 + ty + 8 * r) * 128 + by * 32 + tx] = tile[tx][ty + 8 * r];
}

// log_softmax over dim 1 (i) of (32,128,128), in place. thread = column j.
__global__ __launch_bounds__(128)
void arc_logsoftmax_k(float* __restrict__ arc)
{
    int b = blockIdx.x, j = threadIdx.x;
    float* base = arc + (size_t)b * T_ * T_ + j;
    float m = -INFINITY;
    for (int i = 0; i < T_; ++i) m = fmaxf(m, base[(size_t)i * T_]);
    float s = 0.0f;
    for (int i = 0; i < T_; ++i) s += expf(base[(size_t)i * T_] - m);
    float ls = m + logf(s);
    for (int i = 0; i < T_; ++i) base[(size_t)i * T_] -= ls;
}

// ---------------------------------------------------------------------------
// Fused TL + lab kernel: per (l,b) block computes
//   T = HL_b @ U_lab[l]        (Phase A, T parked in LDS)
//   E_slice = T @ DLt_b        (Phase B, written once)
// Replaces the TL gemm + lab_inplace pair: saves one full write+read
// round-trip of the 104.8 MB E tensor and one kernel launch.
// LDS: T 128x132 (67.6 KB) + 16x132 staging (8.4 KB) = 76 KB -> 2 blocks/CU.
// ---------------------------------------------------------------------------
__global__ __launch_bounds__(256)
void tl_lab_k(const float* __restrict__ HL, const float* __restrict__ Ul,
              const float* __restrict__ dlt, float* __restrict__ E)
{
    __shared__ float T[128 * 132];   // 67.6 KB
    __shared__ float stg[16][132];   // 8.4 KB (A+B slices / DLt slices)
    const int l = blockIdx.x, b = blockIdx.y;
    const int t = threadIdx.x;
    const int tx = t & 15, ty = t >> 4;
    const int j0 = tx * 8, i0 = ty * 8;
    const float* Apan = HL + (size_t)b * 128 * 128;
    const float* Bpan = Ul + (size_t)l * 16384;
    const float* Dpan = dlt + (size_t)b * 16384;
    float acc[8][8] = {};
    // ---- Phase A: T = HL_b @ Ul_l ----
    for (int k0 = 0; k0 < 128; k0 += 8) {
        {
            // A slice: stg[0..7][row] = HL[row][k0+kb] (transposed to k-major)
            int row = t & 127, kb = (t >> 7) * 4;
            float4 a = *(const float4*)&Apan[row * 128 + k0 + kb];
            stg[kb + 0][row] = a.x; stg[kb + 1][row] = a.y;
            stg[kb + 2][row] = a.z; stg[kb + 3][row] = a.w;
            // B slice: stg[8+kk][c4] = Ul[l][k0+kk][c4]
            int kk = t >> 5, c4 = (t & 31) * 4;
            *(float4*)&stg[8 + kk][c4] = *(const float4*)&Bpan[(size_t)(k0 + kk) * 128 + c4];
        }
        __syncthreads();
#pragma unroll
        for (int kk = 0; kk < 8; ++kk) {
            float4 a0 = *(const float4*)&stg[kk][i0];
            float4 a1 = *(const float4*)&stg[kk][i0 + 4];
            float4 b0 = *(const float4*)&stg[8 + kk][j0];
            float4 b1 = *(const float4*)&stg[8 + kk][j0 + 4];
            float av[8] = { a0.x, a0.y, a0.z, a0.w, a1.x, a1.y, a1.z, a1.w };
            float bv[8] = { b0.x, b0.y, b0.z, b0.w, b1.x, b1.y, b1.z, b1.w };
#pragma unroll
            for (int i = 0; i < 8; ++i)
#pragma unroll
                for (int j = 0; j < 8; ++j)
                    acc[i][j] += av[i] * bv[j];
        }
        __syncthreads();
    }
    // park T in LDS
#pragma unroll
    for (int ii = 0; ii < 8; ++ii) {
        float4 o0 = { acc[ii][0], acc[ii][1], acc[ii][2], acc[ii][3] };
        float4 o1 = { acc[ii][4], acc[ii][5], acc[ii][6], acc[ii][7] };
        *(float4*)&T[(i0 + ii) * 132 + j0] = o0;
        *(float4*)&T[(i0 + ii) * 132 + j0 + 4] = o1;
#pragma unroll
        for (int j = 0; j < 8; ++j) acc[ii][j] = 0.0f;
    }
    __syncthreads();
    // ---- Phase B: E_slice = T @ DLt_b ----
    for (int s0 = 0; s0 < 128; s0 += 16) {
        {
            // stage DLt rows s0..s0+15 into stg
            int kk = t >> 4, c8 = (t & 15) * 8;
            *(float4*)&stg[kk][c8] = *(const float4*)&Dpan[(size_t)(s0 + kk) * 128 + c8];
            *(float4*)&stg[kk][c8 + 4] = *(const float4*)&Dpan[(size_t)(s0 + kk) * 128 + c8 + 4];
        }
        __syncthreads();
#pragma unroll
        for (int sh = 0; sh < 4; ++sh) {
            int sb = sh * 4;
            float a[8][4];
#pragma unroll
            for (int ii = 0; ii < 8; ++ii) {
                float4 v = *(const float4*)&T[(i0 + ii) * 132 + s0 + sb];
                a[ii][0] = v.x; a[ii][1] = v.y; a[ii][2] = v.z; a[ii][3] = v.w;
            }
            float bb[4][8];
#pragma unroll
            for (int ss = 0; ss < 4; ++ss) {
                float4 x = *(const float4*)&stg[sb + ss][j0];
                float4 y = *(const float4*)&stg[sb + ss][j0 + 4];
                bb[ss][0] = x.x; bb[ss][1] = x.y; bb[ss][2] = x.z; bb[ss][3] = x.w;
                bb[ss][4] = y.x; bb[ss][5] = y.y; bb[ss][6] = y.z; bb[ss][7] = y.w;
            }
#pragma unroll
            for (int ii = 0; ii < 8; ++ii)
#pragma unroll
                for (int jj = 0; jj < 8; ++jj)
#pragma unroll
                    for (int ss = 0; ss < 4; ++ss)
                        acc[ii][jj] += a[ii][ss] * bb[ss][jj];
        }
        __syncthreads();
    }
    float* base = E + ((size_t)b * L_ + l) * 16384;
#pragma unroll
    for (int ii = 0; ii < 8; ++ii) {
        float4 o0 = { acc[ii][0], acc[ii][1], acc[ii][2], acc[ii][3] };
        float4 o1 = { acc[ii][4], acc[ii][5], acc[ii][6], acc[ii][7] };
        *(float4*)&base[(size_t)(i0 + ii) * 128 + j0] = o0;
        *(float4*)&base[(size_t)(i0 + ii) * 128 + j0 + 4] = o1;
    }
}

// energy combine + fused score/labmax for MST.
__global__ __launch_bounds__(256)
void energy_combine_k(float* __restrict__ E, const float* __restrict__ narc,
                      float* __restrict__ score_g, unsigned char* __restrict__ labmax_g)
{
    int g = blockIdx.x * 256 + threadIdx.x; // 0..524287
    int b = g >> 14;
    int ij = g & 16383;
    float* base = E + (size_t)b * L_ * T_ * T_ + ij;
    float v[L_];
    float m = -INFINITY;
    int am = 0;
#pragma unroll
    for (int l = 0; l < L_; ++l) {
        v[l] = base[(size_t)l * T_ * T_];
        if (v[l] > m) { m = v[l]; am = l; }
    }
    float s = 0.0f;
#pragma unroll
    for (int l = 0; l < L_; ++l) s += expf(v[l] - m);
    float ls = m + logf(s);
    float na = narc[(size_t)b * T_ * T_ + ij];
#pragma unroll
    for (int l = 0; l < L_; ++l) base[(size_t)l * T_ * T_] = expf(na + v[l] - ls);
    int i = ij >> 7, j = ij & 127;
    score_g[(size_t)b * 16384 + ij] = (i == j) ? 0.0f : expf(na + m - ls);
    labmax_g[(size_t)b * 16384 + ij] = (unsigned char)am;
}

// ---------------------------------------------------------------------------
// Chu-Liu-Edmonds MST decode (r7 structure, unchanged — best-known 280 us).
// ---------------------------------------------------------------------------
__global__ __launch_bounds__(256)
void mst_k(const float* __restrict__ score_g, const unsigned char* __restrict__ labmax_g,
           float* __restrict__ heads, float* __restrict__ tags)
{
    const int b = blockIdx.x, t = threadIdx.x;
    __shared__ float score[128 * 129];          // 66 KB, stride 129
    __shared__ unsigned short oio[128 * 129];   // 33 KB: oin | (oout<<8)
    __shared__ unsigned char pstL[96 * 128];    // 12 KB: parents per pass-level
    __shared__ unsigned char kynL[96 * 128];    // 12 KB: key cand per pass-level
    __shared__ int parents[128];
    __shared__ int fe[128]; // -2 = absent; -1 = root marker
    __shared__ float pmx[128];
    __shared__ int pp[128];
    __shared__ float cwacc[128];   // cycle weight by cid
    __shared__ int cnt[128];
    __shared__ int offarr[128];
    __shared__ float Lsub[128];
    __shared__ unsigned char Lnode[128], Lcid[128];
    __shared__ unsigned char cidarr[128], oncyc[128];

    // ---- phase 0: stage score (padded), init oio/fe ----
    {
        const float4* src = (const float4*)(score_g + (size_t)b * 16384);
        for (int i = t; i < 4096; i += 256) {
            float4 v = src[i];
            int r = i >> 5, c = (i & 31) * 4;
            float* d = &score[r * 129 + c];
            d[0] = v.x; d[1] = v.y; d[2] = v.z; d[3] = v.w;
        }
    }
    for (int i = t; i < 16384; i += 256) {
        int r = i >> 7, c = i & 127;
        oio[r * 129 + c] = (unsigned short)(r | (c << 8));
    }
    if (t < 128) { fe[t] = -2; oncyc[t] = 0; }
    __syncthreads();
    if (t < 128) score[t * 129 + t] = -INFINITY; // diag never read elsewhere
    __syncthreads();
    // ---- initial full parent scan (split across 256 threads) ----
    float mxl = 0.0f; int pl = 0;
    if (t >= 128) {
        int col = t - 128;
        float mx = -INFINITY; int pu = 64;
        if (col != 0) {
            mx = score[64 * 129 + col];
#pragma unroll 16
            for (int n2 = 65; n2 < 128; ++n2) {
                float sc = score[n2 * 129 + col];
                if (sc > mx) { mx = sc; pu = n2; }
            }
        }
        pmx[col] = mx; pp[col] = pu;
    } else if (t != 0) {
        mxl = score[t]; pl = 0; // row 0 initial (root candidate)
#pragma unroll 16
        for (int n2 = 1; n2 < 64; ++n2) {
            float sc = score[n2 * 129 + t];
            if (sc > mxl) { mxl = sc; pl = n2; }
        }
    }
    __syncthreads();
    if (t == 0) parents[0] = -1;
    else if (t < 128) parents[t] = (pmx[t] > mxl) ? pp[t] : pl;
    __syncthreads(); // ---- barrier A: wave 0 takes over ----

    if (t < 64) {
        const int n0 = t, n1 = t + 64;
        int p0 = parents[n0], p1 = parents[n1];
        int c0 = 1, c1 = 1;       // active flags
        int r0 = n0, r1 = n1;     // rep_of mirrors
        int lev = 0, nact = 128, pass = 0;
        for (;;) {
            // --- doubling: a = 2^rounds-step ancestor, m = path-min ---
            int rounds = 32 - __clz(nact - 1);
            int a0 = (n0 == 0 || !c0) ? 0 : p0;
            int a1 = (!c1) ? 0 : p1;
            int m0 = n0, m1 = n1;
            for (int s = 0; s < rounds; ++s) {
                int pk0 = (a0 << 7) | m0;
                int pk1 = (a1 << 7) | m1;
                int q00 = __shfl(pk0, a0 & 63, 64);
                int q01 = __shfl(pk1, a0 & 63, 64);
                int q10 = __shfl(pk0, a1 & 63, 64);
                int q11 = __shfl(pk1, a1 & 63, 64);
                int g0 = (a0 & 64) ? q01 : q00;
                int g1 = (a1 & 64) ? q11 : q10;
                a0 = g0 >> 7; int gm0 = g0 & 127; m0 = gm0 < m0 ? gm0 : m0;
                a1 = g1 >> 7; int gm1 = g1 & 127; m1 = gm1 < m1 ? gm1 : m1;
            }
            int pred0 = (n0 >= 1) && c0 && (a0 != 0);
            int pred1 = c1 && (a1 != 0);
            unsigned long long bal0 = __ballot(pred0);
            unsigned long long bal1 = __ballot(pred1);
            if (bal0 == 0ull && bal1 == 0ull) {
                // base case: no cycles — emit final edges for active nodes
                if (n0 == 0) fe[0] = -1;
                else if (c0) { int w = oio[p0 * 129 + n0]; fe[w >> 8] = w & 255; }
                if (c1) { int w = oio[p1 * 129 + n1]; fe[w >> 8] = w & 255; }
                __threadfence_block();
                break;
            }
            // --- mark all cycle nodes; zero per-pass accumulators ---
            unsigned char ep = (unsigned char)(++pass);
            if (pred0) oncyc[a0] = ep;
            if (pred1) oncyc[a1] = ep;
            cnt[n0] = 0; cnt[n1] = 0;
            cwacc[n0] = 0.0f; cwacc[n1] = 0.0f;
            __threadfence_block(); // fence A
            int onc0 = c0 && (oncyc[n0] == ep);
            int onc1 = c1 && (oncyc[n1] == ep);
            const int cid0 = m0, cid1 = m1; // valid when onc
            cidarr[n0] = onc0 ? (unsigned char)cid0 : 0xFF;
            cidarr[n1] = onc1 ? (unsigned char)cid1 : 0xFF;
            float sub0 = 0.0f, sub1 = 0.0f;
            int rk0 = 0, rk1 = 0;
            if (onc0) { sub0 = score[p0 * 129 + n0]; rk0 = atomicAdd(&cnt[cid0], 1); atomicAdd(&cwacc[cid0], sub0); }
            if (onc1) { sub1 = score[p1 * 129 + n1]; rk1 = atomicAdd(&cnt[cid1], 1); atomicAdd(&cwacc[cid1], sub1); }
            __threadfence_block(); // fence B: cnt/cidarr/cwacc final
            // --- packed wave scan of cnt -> segment offsets (cid order) ---
            int x0 = cnt[n0], x1 = cnt[n1];
            int v = (x0 & 0xFFFF) | (x1 << 16);
            for (int off = 1; off < 64; off <<= 1) {
                int u = __shfl(v, t >= off ? t - off : 0, 64);
                v += (t >= off) ? u : 0;
            }
            int tot = __shfl(v, 63, 64);
            int Mtot = (tot & 0xFFFF) + (tot >> 16);
            offarr[n0] = (v & 0xFFFF) - x0;
            offarr[n1] = (tot & 0xFFFF) + ((v >> 16) & 0xFFFF) - x1;
            __threadfence_block(); // fence C: offsets visible
            if (onc0) { int sl = offarr[cid0] + rk0; Lnode[sl] = (unsigned char)n0; Lcid[sl] = (unsigned char)cid0; Lsub[sl] = sub0; }
            if (onc1) { int sl = offarr[cid1] + rk1; Lnode[sl] = (unsigned char)n1; Lcid[sl] = (unsigned char)cid1; Lsub[sl] = sub1; }
            // --- save pass-level state ---
            int rc0 = cidarr[r0], rc1 = cidarr[r1];
            if (lev < 96) {
                pstL[lev * 128 + n0] = (unsigned char)p0;
                pstL[lev * 128 + n1] = (unsigned char)p1;
                kynL[lev * 128 + n0] = (rc0 != 0xFF) ? (unsigned char)r0 : 0xFF;
                kynL[lev * 128 + n1] = (rc1 != 0xFF) ? (unsigned char)r1 : 0xFF;
            }
            if (rc0 != 0xFF) r0 = rc0;
            if (rc1 != 0xFF) r1 = rc1;
            __threadfence_block(); // fence D: list + saved state visible
            // --- Phase 1: all (node, cycle) pairs with rep(c) < cid(node) ---
            {
                int lim0 = c0 ? (onc0 ? cid0 : 256) : -1;
                int lim1 = c1 ? (onc1 ? cid1 : 256) : -1;
                float inw0 = -INFINITY, outw0 = -INFINITY;
                float inw1 = -INFINITY, outw1 = -INFINITY;
                int qi0 = 0, qo0 = 0, qi1 = 0, qo1 = 0;
                int cidC = Lcid[0], mC = Lnode[0];
                float sbC = Lsub[0];
                for (int i = 0; i < Mtot; ++i) {
                    int cidN = 0, mN = 0; float sbN = 0.0f;
                    if (i + 1 < Mtot) { cidN = Lcid[i + 1]; mN = Lnode[i + 1]; sbN = Lsub[i + 1]; }
                    if (cidC < lim0) {
                        float si = score[mC * 129 + n0];
                        float so = score[n0 * 129 + mC] - sbC;
                        int wi = oio[mC * 129 + n0];
                        int wo = oio[n0 * 129 + mC];
                        if (si > inw0) { inw0 = si; qi0 = wi; }
                        if (so > outw0) { outw0 = so; qo0 = wo; }
                    }
                    if (cidC < lim1) {
                        float si = score[mC * 129 + n1];
                        float so = score[n1 * 129 + mC] - sbC;
                        int wi = oio[mC * 129 + n1];
                        int wo = oio[n1 * 129 + mC];
                        if (si > inw1) { inw1 = si; qi1 = wi; }
                        if (so > outw1) { outw1 = so; qo1 = wo; }
                    }
                    int segend = (i + 1 == Mtot) || (cidN != cidC);
                    if (segend) {
                        if (cidC < lim0) {
                            float cwc = cwacc[cidC];
                            score[cidC * 129 + n0] = inw0; oio[cidC * 129 + n0] = (unsigned short)qi0;
                            score[n0 * 129 + cidC] = cwc + outw0; oio[n0 * 129 + cidC] = (unsigned short)qo0;
                        }
                        if (cidC < lim1) {
                            float cwc = cwacc[cidC];
                            score[cidC * 129 + n1] = inw1; oio[cidC * 129 + n1] = (unsigned short)qi1;
                            score[n1 * 129 + cidC] = cwc + outw1; oio[n1 * 129 + cidC] = (unsigned short)qo1;
                        }
                        inw0 = -INFINITY; outw0 = -INFINITY;
                        inw1 = -INFINITY; outw1 = -INFINITY;
                    }
                    cidC = cidN; mC = mN; sbC = sbN;
                }
            }
            __threadfence_block(); // fence E: Phase 1 visible
            // --- Phase 2: rep lanes vs strictly-later cycles ---
            int rp0 = onc0 && (n0 == cid0);
            int rp1 = onc1 && (n1 == cid1);
            unsigned long long q0 = __ballot(rp0);
            unsigned long long q1 = __ballot(rp1);
            int ncyc = (int)__popcll(q0) + (int)__popcll(q1);
            if (ncyc >= 2) {
                float inw0 = -INFINITY, outw0 = -INFINITY;
                float inw1 = -INFINITY, outw1 = -INFINITY;
                int qi0 = 0, qo0 = 0, qi1 = 0, qo1 = 0;
                int cidC = Lcid[0], mC = Lnode[0];
                float sbC = Lsub[0];
                for (int i = 0; i < Mtot; ++i) {
                    int cidN = 0, mN = 0; float sbN = 0.0f;
                    if (i + 1 < Mtot) { cidN = Lcid[i + 1]; mN = Lnode[i + 1]; sbN = Lsub[i + 1]; }
                    int e0 = rp0 && (cidC > cid0);
                    int e1 = rp1 && (cidC > cid1);
                    if (e0) {
                        float si = score[mC * 129 + n0];
                        float so = score[n0 * 129 + mC] - sbC;
                        int wi = oio[mC * 129 + n0];
                        int wo = oio[n0 * 129 + mC];
                        if (si > inw0) { inw0 = si; qi0 = wi; }
                        if (so > outw0) { outw0 = so; qo0 = wo; }
                    }
                    if (e1) {
                        float si = score[mC * 129 + n1];
                        float so = score[n1 * 129 + mC] - sbC;
                        int wi = oio[mC * 129 + n1];
                        int wo = oio[n1 * 129 + mC];
                        if (si > inw1) { inw1 = si; qi1 = wi; }
                        if (so > outw1) { outw1 = so; qo1 = wo; }
                    }
                    int segend = (i + 1 == Mtot) || (cidN != cidC);
                    if (segend) {
                        if (e0) {
                            float cwc = cwacc[cidC];
                            score[cidC * 129 + n0] = inw0; oio[cidC * 129 + n0] = (unsigned short)qi0;
                            score[n0 * 129 + cidC] = cwc + outw0; oio[n0 * 129 + cidC] = (unsigned short)qo0;
                        }
                        if (e1) {
                            float cwc = cwacc[cidC];
                            score[cidC * 129 + n1] = inw1; oio[cidC * 129 + n1] = (unsigned short)qi1;
                            score[n1 * 129 + cidC] = cwc + outw1; oio[n1 * 129 + cidC] = (unsigned short)qo1;
                        }
                        inw0 = -INFINITY; outw0 = -INFINITY;
                        inw1 = -INFINITY; outw1 = -INFINITY;
                    }
                    cidC = cidN; mC = mN; sbC = sbN;
                }
                __threadfence_block(); // fence F: Phase 2 visible
            }
            // --- deactivate dying members; remap parents into reps ---
            if (onc0 && n0 != cid0) c0 = 0;
            if (onc1 && n1 != cid1) c1 = 0;
            if (c0 && n0 != 0) { int cp = cidarr[p0]; if (cp != 0xFF) p0 = cp; }
            if (c1)            { int cp = cidarr[p1]; if (cp != 0xFF) p1 = cp; }
            // --- surviving reps: column rescans, 2 butterflies interleaved ---
            {
                unsigned long long w0 = q0, w1 = q1;
                while (w0 | w1) {
                    int repA, repB = -1;
                    if (w0) { repA = (int)__ffsll((long long)w0) - 1; w0 &= w0 - 1; }
                    else    { repA = 64 + (int)__ffsll((long long)w1) - 1; w1 &= w1 - 1; }
                    if (w0) { repB = (int)__ffsll((long long)w0) - 1; w0 &= w0 - 1; }
                    else if (w1) { repB = 64 + (int)__ffsll((long long)w1) - 1; w1 &= w1 - 1; }
                    float aA = c0 ? score[n0 * 129 + repA] : -INFINITY;
                    float bA = c1 ? score[n1 * 129 + repA] : -INFINITY;
                    float aB = -INFINITY, bB = -INFINITY;
                    if (repB >= 0) {
                        aB = c0 ? score[n0 * 129 + repB] : -INFINITY;
                        bB = c1 ? score[n1 * 129 + repB] : -INFINITY;
                    }
                    float vA; int iA;
                    if (bA > aA) { vA = bA; iA = n1; } else { vA = aA; iA = n0; }
                    float vB; int iB;
                    if (bB > aB) { vB = bB; iB = n1; } else { vB = aB; iB = n0; }
#pragma unroll
                    for (int off = 32; off >= 1; off >>= 1) {
                        float oA = __shfl_xor(vA, off, 64);
                        int jA = __shfl_xor(iA, off, 64);
                        float oB = __shfl_xor(vB, off, 64);
                        int jB = __shfl_xor(iB, off, 64);
                        if (oA > vA || (oA == vA && jA < iA)) { vA = oA; iA = jA; }
                        if (oB > vB || (oB == vB && jB < iB)) { vB = oB; iB = jB; }
                    }
                    if (n0 == repA) p0 = iA;
                    if (n1 == repA) p1 = iA;
                    if (repB >= 0) {
                        if (n0 == repB) p0 = iB;
                        if (n1 == repB) p1 = iB;
                    }
                }
            }
            nact -= (Mtot - ncyc);
            ++lev;
        }
        // --- unwind: per-pass levels, disjoint parallel walks ---
        int ltop = lev < 96 ? lev : 96;
        for (int l2 = ltop - 1; l2 >= 0; --l2) {
            int ky0 = kynL[l2 * 128 + n0], ky1 = kynL[l2 * 128 + n1];
            int cand0 = (ky0 != 0xFF) && (fe[n0] != -2);
            int cand1 = (ky1 != 0xFF) && (fe[n1] != -2);
            if (cand0) {
                int key = ky0;
                int prev = pstL[l2 * 128 + key];
                int guard = 0;
                while (prev != key && guard++ < 130) {
                    int pp2 = pstL[l2 * 128 + prev];
                    int w = oio[pp2 * 129 + prev];
                    fe[w >> 8] = w & 255;
                    prev = pp2;
                }
            }
            if (cand1) {
                int key = ky1;
                int prev = pstL[l2 * 128 + key];
                int guard = 0;
                while (prev != key && guard++ < 130) {
                    int pp2 = pstL[l2 * 128 + prev];
                    int w = oio[pp2 * 129 + prev];
                    fe[w >> 8] = w & 255;
                    prev = pp2;
                }
            }
            __threadfence_block();
        }
    }
    __syncthreads(); // ---- barrier B: waves 1-3 rejoin ----

    // --- emit heads / head_type ---
    if (t < 128) {
        int f = fe[t];
        float h, ht;
        if (f != -2) {
            h = (float)f;
            int prow = (f < 0) ? 127 : f; // numpy negative-index semantics for root
            ht = (float)(int)labmax_g[(size_t)b * 16384 + prow * 128 + t];
        } else { h = 0.0f; ht = 1.0f; }
        heads[b * 128 + t] = h;
        tags[b * 128 + t] = ht;
    }
}

extern "C" void kernel_launch(void* const* d_in, const int* in_sizes, int n_in,
                              void* d_out, int out_size, void* d_ws, size_t ws_size,
                              hipStream_t stream)
{
    const float* X   = (const float*)d_in[0];
    const float* Wha = (const float*)d_in[1];
    const float* bha = (const float*)d_in[2];
    const float* Wda = (const float*)d_in[3];
    const float* bda = (const float*)d_in[4];
    const float* Ua  = (const float*)d_in[5];
    const float* Whl = (const float*)d_in[6];
    const float* bhl = (const float*)d_in[7];
    const float* Wdl = (const float*)d_in[8];
    const float* bdl = (const float*)d_in[9];
    const float* Ul  = (const float*)d_in[10];
    // d_in[11] = mask: all-ones in this problem; length = 128 per batch.

    char* ws = (char*)d_ws;
    float* HA    = (float*)(ws + (size_t)0);
    float* DA    = (float*)(ws + ((size_t)8 << 20));
    float* TA    = (float*)(ws + ((size_t)16 << 20));
    float* HL    = (float*)(ws + ((size_t)24 << 20));
    float* DL    = (float*)(ws + ((size_t)26 << 20));
    float* DLt   = (float*)(ws + ((size_t)28 << 20));
    float* ARC   = (float*)(ws + ((size_t)30 << 20));
    float* SCORE = (float*)(ws + ((size_t)32 << 20));                  // 2 MB
    unsigned char* LABMAX = (unsigned char*)(ws + ((size_t)34 << 20)); // 512 KB

    float* E     = (float*)d_out;
    float* heads = E + (size_t)B_ * L_ * T_ * T_;
    float* tags  = heads + (size_t)B_ * T_;

    dim3 thr(256);
    // fused projections + bias + ELU (one launch, 640 blocks)
    proj_gemm_k<<<dim3(10, 64), thr, 0, stream>>>(X, Wha, bha, Wda, bda, Whl, bhl, Wdl, bdl,
                                                  HA, DA, HL, DL);
    // TA = HA @ U_arc
    gemm_k<<<dim3(4, 64, 1), thr, 0, stream>>>(HA, Ua, nullptr, TA, 512, 512, 512, 512, 0, 0, 0, (long long)128 * 512, 0);
    // DLt[b][s][j]
    transpose_k<<<dim3(4, 4, 32), dim3(32, 8), 0, stream>>>(DL, DLt);
    // arc_scores[b] = TA_b @ DA_b^T
    gemm_k<<<dim3(1, 2, 32), thr, 0, stream>>>(TA, DA, nullptr, ARC, 512, 512, 512, 128, 65536, 65536, 16384, 0, 4);
    // log_softmax over i, in place
    arc_logsoftmax_k<<<32, 128, 0, stream>>>(ARC);
    // fused: E[b,l] = (HL_b @ U_lab[l]) @ DLt_b  (replaces TL gemm + lab_inplace)
    tl_lab_k<<<dim3(50, 32), thr, 0, stream>>>(HL, Ul, DLt, E);
    // label log-softmax + combine with norm_arc + exp + fused score/argmax
    energy_combine_k<<<2048, 256, 0, stream>>>(E, ARC, SCORE, LABMAX);
    // MST decode (all cycles per pass, two-sweep sequential-equivalent)
    mst_k<<<32, 256, 0, stream>>>(SCORE, LABMAX, heads, tags);
}

// Round 8
// 879.577 us; speedup vs baseline: 1.0884x; 1.0884x over previous
//
#include <hip/hip_runtime.h>
#include <math.h>

#define B_ 32
#define T_ 128
#define D_ 768
#define A_ 512
#define R_ 128
#define L_ 50

// ---------------------------------------------------------------------------
// Fused projection GEMM: HA/DA/HL/DL = ELU(X @ W + b) in one launch.
// ---------------------------------------------------------------------------
__global__ __launch_bounds__(256)
void proj_gemm_k(const float* __restrict__ X,
                 const float* __restrict__ Wha, const float* __restrict__ bha,
                 const float* __restrict__ Wda, const float* __restrict__ bda,
                 const float* __restrict__ Whl, const float* __restrict__ bhl,
                 const float* __restrict__ Wdl, const float* __restrict__ bdl,
                 float* __restrict__ HA, float* __restrict__ DA,
                 float* __restrict__ HL, float* __restrict__ DL)
{
    __shared__ float As[16][68];
    __shared__ float Bs[16][132];
    const int bx = blockIdx.x;
    const float *W, *bias; float* C; int ld, ncol;
    if (bx < 4)      { W = Wha; bias = bha; C = HA; ld = 512; ncol = bx * 128; }
    else if (bx < 8) { W = Wda; bias = bda; C = DA; ld = 512; ncol = (bx - 4) * 128; }
    else if (bx == 8){ W = Whl; bias = bhl; C = HL; ld = 128; ncol = 0; }
    else             { W = Wdl; bias = bdl; C = DL; ld = 128; ncol = 0; }
    const int m0 = blockIdx.y * 64;
    const int tid = threadIdx.x;
    const int tx = tid & 15, ry = tid >> 4;
    float acc[4][8] = {};
    for (int k0 = 0; k0 < 768; k0 += 16) {
        {
            int row = tid >> 2, kb = (tid & 3) * 4;
            float4 a = *(const float4*)&X[(size_t)(m0 + row) * 768 + k0 + kb];
            As[kb + 0][row] = a.x; As[kb + 1][row] = a.y;
            As[kb + 2][row] = a.z; As[kb + 3][row] = a.w;
        }
        {
            int kk = tid >> 4, c0 = (tid & 15) * 4;
            const float* Bp = &W[(size_t)(k0 + kk) * ld + ncol + c0];
            *(float4*)&Bs[kk][c0] = *(const float4*)&Bp[0];
            *(float4*)&Bs[kk][c0 + 64] = *(const float4*)&Bp[64];
        }
        __syncthreads();
#pragma unroll
        for (int kk = 0; kk < 16; ++kk) {
            float4 a4 = *(const float4*)&As[kk][ry * 4];
            float4 b0 = *(const float4*)&Bs[kk][tx * 4];
            float4 b1 = *(const float4*)&Bs[kk][tx * 4 + 64];
            float av[4] = { a4.x, a4.y, a4.z, a4.w };
            float bv[8] = { b0.x, b0.y, b0.z, b0.w, b1.x, b1.y, b1.z, b1.w };
#pragma unroll
            for (int i = 0; i < 4; ++i)
#pragma unroll
                for (int j = 0; j < 8; ++j)
                    acc[i][j] += av[i] * bv[j];
        }
        __syncthreads();
    }
    float bv0[8];
    {
        float4 q0 = *(const float4*)&bias[ncol + tx * 4];
        float4 q1 = *(const float4*)&bias[ncol + tx * 4 + 64];
        bv0[0] = q0.x; bv0[1] = q0.y; bv0[2] = q0.z; bv0[3] = q0.w;
        bv0[4] = q1.x; bv0[5] = q1.y; bv0[6] = q1.z; bv0[7] = q1.w;
    }
#pragma unroll
    for (int i = 0; i < 4; ++i) {
        int m = m0 + ry * 4 + i;
        size_t base = (size_t)m * ld + ncol;
        float o[8];
#pragma unroll
        for (int j = 0; j < 8; ++j) {
            float v = acc[i][j] + bv0[j];
            o[j] = v > 0.0f ? v : expm1f(v);
        }
        float4 s0 = { o[0], o[1], o[2], o[3] };
        float4 s1 = { o[4], o[5], o[6], o[7] };
        *(float4*)&C[base + tx * 4] = s0;
        *(float4*)&C[base + tx * 4 + 64] = s1;
    }
}

// ---------------------------------------------------------------------------
// fp32 GEMM, tile 64x128, 256 threads, 4x8 acc/thread, b128 LDS reads.
// ---------------------------------------------------------------------------
__global__ __launch_bounds__(256)
void gemm_k(const float* __restrict__ A, const float* __restrict__ B,
            const float* __restrict__ bias, float* __restrict__ C,
            int K, int lda, int ldb, int ldc,
            long long sA, long long sB, long long sC, long long c_outer, int flags)
{
    __shared__ float As[16][68];
    __shared__ float Bs[16][132];
    A += (size_t)blockIdx.z * sA;
    B += (size_t)blockIdx.z * sB;
    C += (size_t)blockIdx.z * sC;
    const int m0 = blockIdx.y * 64, n0 = blockIdx.x * 128;
    const int tid = threadIdx.x;
    const int tx = tid & 15, ry = tid >> 4;
    float acc[4][8] = {};
    for (int k0 = 0; k0 < K; k0 += 16) {
        {
            int row = tid >> 2, kb = (tid & 3) * 4;
            float4 a = *(const float4*)&A[(size_t)(m0 + row) * lda + k0 + kb];
            As[kb + 0][row] = a.x; As[kb + 1][row] = a.y;
            As[kb + 2][row] = a.z; As[kb + 3][row] = a.w;
        }
        if (!(flags & 4)) {
            int kk = tid >> 4, c0 = (tid & 15) * 4;
            const float* Bp = &B[(size_t)(k0 + kk) * ldb + n0 + c0];
            *(float4*)&Bs[kk][c0] = *(const float4*)&Bp[0];
            *(float4*)&Bs[kk][c0 + 64] = *(const float4*)&Bp[64];
        } else {
            int col = tid >> 1, kb = (tid & 1) * 8;
            const float* Bp = &B[(size_t)(n0 + col) * ldb + k0 + kb];
            float4 b0 = *(const float4*)&Bp[0];
            float4 b1 = *(const float4*)&Bp[4];
            Bs[kb + 0][col] = b0.x; Bs[kb + 1][col] = b0.y;
            Bs[kb + 2][col] = b0.z; Bs[kb + 3][col] = b0.w;
            Bs[kb + 4][col] = b1.x; Bs[kb + 5][col] = b1.y;
            Bs[kb + 6][col] = b1.z; Bs[kb + 7][col] = b1.w;
        }
        __syncthreads();
#pragma unroll
        for (int kk = 0; kk < 16; ++kk) {
            float4 a4 = *(const float4*)&As[kk][ry * 4];
            float4 b0 = *(const float4*)&Bs[kk][tx * 4];
            float4 b1 = *(const float4*)&Bs[kk][tx * 4 + 64];
            float av[4] = { a4.x, a4.y, a4.z, a4.w };
            float bv[8] = { b0.x, b0.y, b0.z, b0.w, b1.x, b1.y, b1.z, b1.w };
#pragma unroll
            for (int i = 0; i < 4; ++i)
#pragma unroll
                for (int j = 0; j < 8; ++j)
                    acc[i][j] += av[i] * bv[j];
        }
        __syncthreads();
    }
    float bv0[8] = {};
    if (flags & 1) {
        float4 q0 = *(const float4*)&bias[n0 + tx * 4];
        float4 q1 = *(const float4*)&bias[n0 + tx * 4 + 64];
        bv0[0] = q0.x; bv0[1] = q0.y; bv0[2] = q0.z; bv0[3] = q0.w;
        bv0[4] = q1.x; bv0[5] = q1.y; bv0[6] = q1.z; bv0[7] = q1.w;
    }
#pragma unroll
    for (int i = 0; i < 4; ++i) {
        int m = m0 + ry * 4 + i;
        size_t base = (size_t)(m >> 7) * c_outer + (size_t)(m & 127) * ldc + n0;
        float o[8];
#pragma unroll
        for (int j = 0; j < 8; ++j) {
            float v = acc[i][j] + bv0[j];
            if (flags & 2) v = v > 0.0f ? v : expm1f(v);
            o[j] = v;
        }
        float4 s0 = { o[0], o[1], o[2], o[3] };
        float4 s1 = { o[4], o[5], o[6], o[7] };
        *(float4*)&C[base + tx * 4] = s0;
        *(float4*)&C[base + tx * 4 + 64] = s1;
    }
}

// 128x128 per-batch transpose: DLt[b][s][j] = DL[b][j][s]
__global__ __launch_bounds__(256)
void transpose_k(const float* __restrict__ in, float* __restrict__ out)
{
    __shared__ float tile[32][33];
    int b = blockIdx.z;
    int bx = blockIdx.x, by = blockIdx.y;
    int tx = threadIdx.x, ty = threadIdx.y; // (32,8)
    const float* src = in + (size_t)b * T_ * R_;
    float* dst = out + (size_t)b * T_ * R_;
#pragma unroll
    for (int r = 0; r < 4; ++r)
        tile[ty + 8 * r][tx] = src[(size_t)(by * 32 + ty + 8 * r) * 128 + bx * 32 + tx];
    __syncthreads();
#pragma unroll
    for (int r = 0; r < 4; ++r)
        dst[(size_t)(bx * 32 + ty + 8 * r) * 128 + by * 32 + tx] = tile[tx][ty + 8 * r];
}

// log_softmax over dim 1 (i) of (32,128,128), in place. thread = column j.
__global__ __launch_bounds__(128)
void arc_logsoftmax_k(float* __restrict__ arc)
{
    int b = blockIdx.x, j = threadIdx.x;
    float* base = arc + (size_t)b * T_ * T_ + j;
    float m = -INFINITY;
    for (int i = 0; i < T_; ++i) m = fmaxf(m, base[(size_t)i * T_]);
    float s = 0.0f;
    for (int i = 0; i < T_; ++i) s += expf(base[(size_t)i * T_] - m);
    float ls = m + logf(s);
    for (int i = 0; i < T_; ++i) base[(size_t)i * T_] -= ls;
}

// ---------------------------------------------------------------------------
// Fused TL + lab kernel v2: two chained gemm_k bodies.
// Per (l, b, half) block (64x128 tile):
//   Phase A: T64 = HL_b[m0:m0+64] @ Ul_l     (gemm_k body, As/Bs staging)
//   park:    Ts[s][row] (k-major, stride 68) — the As layout Phase B needs
//   Phase B: E64 = T64 @ DLt_b               (gemm_k body, A-reads from Ts)
// All hot-loop LDS patterns identical to proven gemm_k (2-way max).
// LDS: Ts 34.8K + As 4.3K + Bs 8.4K = 47.6 KB -> 3 blocks/CU, 12 waves.
// ---------------------------------------------------------------------------
__global__ __launch_bounds__(256)
void tl_lab_k(const float* __restrict__ HL, const float* __restrict__ Ul,
              const float* __restrict__ dlt, float* __restrict__ E)
{
    __shared__ float Ts[128 * 68];  // 34816 B: [s][row], k-major for Phase B
    __shared__ float As[16][68];
    __shared__ float Bs[16][132];
    const int l = blockIdx.x, b = blockIdx.y;
    const int m0 = blockIdx.z * 64;
    const int tid = threadIdx.x;
    const int tx = tid & 15, ry = tid >> 4;
    const float* Apan = HL + (size_t)b * 16384 + (size_t)m0 * 128;
    const float* Bpan = Ul + (size_t)l * 16384;
    const float* Dpan = dlt + (size_t)b * 16384;
    float acc[4][8] = {};
    // ---- Phase A: T64 = HL_b[m0:m0+64] @ Ul_l (gemm_k body, K=128) ----
    for (int k0 = 0; k0 < 128; k0 += 16) {
        {
            int row = tid >> 2, kb = (tid & 3) * 4;
            float4 a = *(const float4*)&Apan[(size_t)row * 128 + k0 + kb];
            As[kb + 0][row] = a.x; As[kb + 1][row] = a.y;
            As[kb + 2][row] = a.z; As[kb + 3][row] = a.w;
        }
        {
            int kk = tid >> 4, c0 = (tid & 15) * 4;
            const float* Bp = &Bpan[(size_t)(k0 + kk) * 128 + c0];
            *(float4*)&Bs[kk][c0] = *(const float4*)&Bp[0];
            *(float4*)&Bs[kk][c0 + 64] = *(const float4*)&Bp[64];
        }
        __syncthreads();
#pragma unroll
        for (int kk = 0; kk < 16; ++kk) {
            float4 a4 = *(const float4*)&As[kk][ry * 4];
            float4 b0 = *(const float4*)&Bs[kk][tx * 4];
            float4 b1 = *(const float4*)&Bs[kk][tx * 4 + 64];
            float av[4] = { a4.x, a4.y, a4.z, a4.w };
            float bv[8] = { b0.x, b0.y, b0.z, b0.w, b1.x, b1.y, b1.z, b1.w };
#pragma unroll
            for (int i = 0; i < 4; ++i)
#pragma unroll
                for (int j = 0; j < 8; ++j)
                    acc[i][j] += av[i] * bv[j];
        }
        __syncthreads();
    }
    // ---- park T64 into Ts[s][row] (k-major; one-time 8 writes/thread) ----
#pragma unroll
    for (int j = 0; j < 8; ++j) {
        int col = (j < 4) ? (tx * 4 + j) : (64 + tx * 4 + j - 4);
        float4 w = { acc[0][j], acc[1][j], acc[2][j], acc[3][j] };
        *(float4*)&Ts[col * 68 + ry * 4] = w;
#pragma unroll
        for (int i = 0; i < 4; ++i) acc[i][j] = 0.0f;
    }
    __syncthreads();
    // ---- Phase B: E64 = T64 @ DLt_b (gemm_k body; A from Ts, no restage) ----
    for (int k0 = 0; k0 < 128; k0 += 16) {
        {
            int kk = tid >> 4, c0 = (tid & 15) * 4;
            const float* Bp = &Dpan[(size_t)(k0 + kk) * 128 + c0];
            *(float4*)&Bs[kk][c0] = *(const float4*)&Bp[0];
            *(float4*)&Bs[kk][c0 + 64] = *(const float4*)&Bp[64];
        }
        __syncthreads();
#pragma unroll
        for (int kk = 0; kk < 16; ++kk) {
            float4 a4 = *(const float4*)&Ts[(k0 + kk) * 68 + ry * 4];
            float4 b0 = *(const float4*)&Bs[kk][tx * 4];
            float4 b1 = *(const float4*)&Bs[kk][tx * 4 + 64];
            float av[4] = { a4.x, a4.y, a4.z, a4.w };
            float bv[8] = { b0.x, b0.y, b0.z, b0.w, b1.x, b1.y, b1.z, b1.w };
#pragma unroll
            for (int i = 0; i < 4; ++i)
#pragma unroll
                for (int j = 0; j < 8; ++j)
                    acc[i][j] += av[i] * bv[j];
        }
        __syncthreads();
    }
    float* base = E + ((size_t)b * L_ + l) * 16384 + (size_t)m0 * 128;
#pragma unroll
    for (int i = 0; i < 4; ++i) {
        float4 s0 = { acc[i][0], acc[i][1], acc[i][2], acc[i][3] };
        float4 s1 = { acc[i][4], acc[i][5], acc[i][6], acc[i][7] };
        *(float4*)&base[(size_t)(ry * 4 + i) * 128 + tx * 4] = s0;
        *(float4*)&base[(size_t)(ry * 4 + i) * 128 + tx * 4 + 64] = s1;
    }
}

// energy combine + fused score/labmax for MST.
__global__ __launch_bounds__(256)
void energy_combine_k(float* __restrict__ E, const float* __restrict__ narc,
                      float* __restrict__ score_g, unsigned char* __restrict__ labmax_g)
{
    int g = blockIdx.x * 256 + threadIdx.x; // 0..524287
    int b = g >> 14;
    int ij = g & 16383;
    float* base = E + (size_t)b * L_ * T_ * T_ + ij;
    float v[L_];
    float m = -INFINITY;
    int am = 0;
#pragma unroll
    for (int l = 0; l < L_; ++l) {
        v[l] = base[(size_t)l * T_ * T_];
        if (v[l] > m) { m = v[l]; am = l; }
    }
    float s = 0.0f;
#pragma unroll
    for (int l = 0; l < L_; ++l) s += expf(v[l] - m);
    float ls = m + logf(s);
    float na = narc[(size_t)b * T_ * T_ + ij];
#pragma unroll
    for (int l = 0; l < L_; ++l) base[(size_t)l * T_ * T_] = expf(na + v[l] - ls);
    int i = ij >> 7, j = ij & 127;
    score_g[(size_t)b * 16384 + ij] = (i == j) ? 0.0f : expf(na + m - ls);
    labmax_g[(size_t)b * 16384 + ij] = (unsigned char)am;
}

// ---------------------------------------------------------------------------
// Chu-Liu-Edmonds MST decode (r7 structure, unchanged — best-known ~280 us).
// ---------------------------------------------------------------------------
__global__ __launch_bounds__(256)
void mst_k(const float* __restrict__ score_g, const unsigned char* __restrict__ labmax_g,
           float* __restrict__ heads, float* __restrict__ tags)
{
    const int b = blockIdx.x, t = threadIdx.x;
    __shared__ float score[128 * 129];          // 66 KB, stride 129
    __shared__ unsigned short oio[128 * 129];   // 33 KB: oin | (oout<<8)
    __shared__ unsigned char pstL[96 * 128];    // 12 KB: parents per pass-level
    __shared__ unsigned char kynL[96 * 128];    // 12 KB: key cand per pass-level
    __shared__ int parents[128];
    __shared__ int fe[128]; // -2 = absent; -1 = root marker
    __shared__ float pmx[128];
    __shared__ int pp[128];
    __shared__ float cwacc[128];   // cycle weight by cid
    __shared__ int cnt[128];
    __shared__ int offarr[128];
    __shared__ float Lsub[128];
    __shared__ unsigned char Lnode[128], Lcid[128];
    __shared__ unsigned char cidarr[128], oncyc[128];

    // ---- phase 0: stage score (padded), init oio/fe ----
    {
        const float4* src = (const float4*)(score_g + (size_t)b * 16384);
        for (int i = t; i < 4096; i += 256) {
            float4 v = src[i];
            int r = i >> 5, c = (i & 31) * 4;
            float* d = &score[r * 129 + c];
            d[0] = v.x; d[1] = v.y; d[2] = v.z; d[3] = v.w;
        }
    }
    for (int i = t; i < 16384; i += 256) {
        int r = i >> 7, c = i & 127;
        oio[r * 129 + c] = (unsigned short)(r | (c << 8));
    }
    if (t < 128) { fe[t] = -2; oncyc[t] = 0; }
    __syncthreads();
    if (t < 128) score[t * 129 + t] = -INFINITY; // diag never read elsewhere
    __syncthreads();
    // ---- initial full parent scan (split across 256 threads) ----
    float mxl = 0.0f; int pl = 0;
    if (t >= 128) {
        int col = t - 128;
        float mx = -INFINITY; int pu = 64;
        if (col != 0) {
            mx = score[64 * 129 + col];
#pragma unroll 16
            for (int n2 = 65; n2 < 128; ++n2) {
                float sc = score[n2 * 129 + col];
                if (sc > mx) { mx = sc; pu = n2; }
            }
        }
        pmx[col] = mx; pp[col] = pu;
    } else if (t != 0) {
        mxl = score[t]; pl = 0; // row 0 initial (root candidate)
#pragma unroll 16
        for (int n2 = 1; n2 < 64; ++n2) {
            float sc = score[n2 * 129 + t];
            if (sc > mxl) { mxl = sc; pl = n2; }
        }
    }
    __syncthreads();
    if (t == 0) parents[0] = -1;
    else if (t < 128) parents[t] = (pmx[t] > mxl) ? pp[t] : pl;
    __syncthreads(); // ---- barrier A: wave 0 takes over ----

    if (t < 64) {
        const int n0 = t, n1 = t + 64;
        int p0 = parents[n0], p1 = parents[n1];
        int c0 = 1, c1 = 1;       // active flags
        int r0 = n0, r1 = n1;     // rep_of mirrors
        int lev = 0, nact = 128, pass = 0;
        for (;;) {
            // --- doubling: a = 2^rounds-step ancestor, m = path-min ---
            int rounds = 32 - __clz(nact - 1);
            int a0 = (n0 == 0 || !c0) ? 0 : p0;
            int a1 = (!c1) ? 0 : p1;
            int m0 = n0, m1 = n1;
            for (int s = 0; s < rounds; ++s) {
                int pk0 = (a0 << 7) | m0;
                int pk1 = (a1 << 7) | m1;
                int q00 = __shfl(pk0, a0 & 63, 64);
                int q01 = __shfl(pk1, a0 & 63, 64);
                int q10 = __shfl(pk0, a1 & 63, 64);
                int q11 = __shfl(pk1, a1 & 63, 64);
                int g0 = (a0 & 64) ? q01 : q00;
                int g1 = (a1 & 64) ? q11 : q10;
                a0 = g0 >> 7; int gm0 = g0 & 127; m0 = gm0 < m0 ? gm0 : m0;
                a1 = g1 >> 7; int gm1 = g1 & 127; m1 = gm1 < m1 ? gm1 : m1;
            }
            int pred0 = (n0 >= 1) && c0 && (a0 != 0);
            int pred1 = c1 && (a1 != 0);
            unsigned long long bal0 = __ballot(pred0);
            unsigned long long bal1 = __ballot(pred1);
            if (bal0 == 0ull && bal1 == 0ull) {
                // base case: no cycles — emit final edges for active nodes
                if (n0 == 0) fe[0] = -1;
                else if (c0) { int w = oio[p0 * 129 + n0]; fe[w >> 8] = w & 255; }
                if (c1) { int w = oio[p1 * 129 + n1]; fe[w >> 8] = w & 255; }
                __threadfence_block();
                break;
            }
            // --- mark all cycle nodes; zero per-pass accumulators ---
            unsigned char ep = (unsigned char)(++pass);
            if (pred0) oncyc[a0] = ep;
            if (pred1) oncyc[a1] = ep;
            cnt[n0] = 0; cnt[n1] = 0;
            cwacc[n0] = 0.0f; cwacc[n1] = 0.0f;
            __threadfence_block(); // fence A
            int onc0 = c0 && (oncyc[n0] == ep);
            int onc1 = c1 && (oncyc[n1] == ep);
            const int cid0 = m0, cid1 = m1; // valid when onc
            cidarr[n0] = onc0 ? (unsigned char)cid0 : 0xFF;
            cidarr[n1] = onc1 ? (unsigned char)cid1 : 0xFF;
            float sub0 = 0.0f, sub1 = 0.0f;
            int rk0 = 0, rk1 = 0;
            if (onc0) { sub0 = score[p0 * 129 + n0]; rk0 = atomicAdd(&cnt[cid0], 1); atomicAdd(&cwacc[cid0], sub0); }
            if (onc1) { sub1 = score[p1 * 129 + n1]; rk1 = atomicAdd(&cnt[cid1], 1); atomicAdd(&cwacc[cid1], sub1); }
            __threadfence_block(); // fence B: cnt/cidarr/cwacc final
            // --- packed wave scan of cnt -> segment offsets (cid order) ---
            int x0 = cnt[n0], x1 = cnt[n1];
            int v = (x0 & 0xFFFF) | (x1 << 16);
            for (int off = 1; off < 64; off <<= 1) {
                int u = __shfl(v, t >= off ? t - off : 0, 64);
                v += (t >= off) ? u : 0;
            }
            int tot = __shfl(v, 63, 64);
            int Mtot = (tot & 0xFFFF) + (tot >> 16);
            offarr[n0] = (v & 0xFFFF) - x0;
            offarr[n1] = (tot & 0xFFFF) + ((v >> 16) & 0xFFFF) - x1;
            __threadfence_block(); // fence C: offsets visible
            if (onc0) { int sl = offarr[cid0] + rk0; Lnode[sl] = (unsigned char)n0; Lcid[sl] = (unsigned char)cid0; Lsub[sl] = sub0; }
            if (onc1) { int sl = offarr[cid1] + rk1; Lnode[sl] = (unsigned char)n1; Lcid[sl] = (unsigned char)cid1; Lsub[sl] = sub1; }
            // --- save pass-level state ---
            int rc0 = cidarr[r0], rc1 = cidarr[r1];
            if (lev < 96) {
                pstL[lev * 128 + n0] = (unsigned char)p0;
                pstL[lev * 128 + n1] = (unsigned char)p1;
                kynL[lev * 128 + n0] = (rc0 != 0xFF) ? (unsigned char)r0 : 0xFF;
                kynL[lev * 128 + n1] = (rc1 != 0xFF) ? (unsigned char)r1 : 0xFF;
            }
            if (rc0 != 0xFF) r0 = rc0;
            if (rc1 != 0xFF) r1 = rc1;
            __threadfence_block(); // fence D: list + saved state visible
            // --- Phase 1: all (node, cycle) pairs with rep(c) < cid(node) ---
            {
                int lim0 = c0 ? (onc0 ? cid0 : 256) : -1;
                int lim1 = c1 ? (onc1 ? cid1 : 256) : -1;
                float inw0 = -INFINITY, outw0 = -INFINITY;
                float inw1 = -INFINITY, outw1 = -INFINITY;
                int qi0 = 0, qo0 = 0, qi1 = 0, qo1 = 0;
                int cidC = Lcid[0], mC = Lnode[0];
                float sbC = Lsub[0];
                for (int i = 0; i < Mtot; ++i) {
                    int cidN = 0, mN = 0; float sbN = 0.0f;
                    if (i + 1 < Mtot) { cidN = Lcid[i + 1]; mN = Lnode[i + 1]; sbN = Lsub[i + 1]; }
                    if (cidC < lim0) {
                        float si = score[mC * 129 + n0];
                        float so = score[n0 * 129 + mC] - sbC;
                        int wi = oio[mC * 129 + n0];
                        int wo = oio[n0 * 129 + mC];
                        if (si > inw0) { inw0 = si; qi0 = wi; }
                        if (so > outw0) { outw0 = so; qo0 = wo; }
                    }
                    if (cidC < lim1) {
                        float si = score[mC * 129 + n1];
                        float so = score[n1 * 129 + mC] - sbC;
                        int wi = oio[mC * 129 + n1];
                        int wo = oio[n1 * 129 + mC];
                        if (si > inw1) { inw1 = si; qi1 = wi; }
                        if (so > outw1) { outw1 = so; qo1 = wo; }
                    }
                    int segend = (i + 1 == Mtot) || (cidN != cidC);
                    if (segend) {
                        if (cidC < lim0) {
                            float cwc = cwacc[cidC];
                            score[cidC * 129 + n0] = inw0; oio[cidC * 129 + n0] = (unsigned short)qi0;
                            score[n0 * 129 + cidC] = cwc + outw0; oio[n0 * 129 + cidC] = (unsigned short)qo0;
                        }
                        if (cidC < lim1) {
                            float cwc = cwacc[cidC];
                            score[cidC * 129 + n1] = inw1; oio[cidC * 129 + n1] = (unsigned short)qi1;
                            score[n1 * 129 + cidC] = cwc + outw1; oio[n1 * 129 + cidC] = (unsigned short)qo1;
                        }
                        inw0 = -INFINITY; outw0 = -INFINITY;
                        inw1 = -INFINITY; outw1 = -INFINITY;
                    }
                    cidC = cidN; mC = mN; sbC = sbN;
                }
            }
            __threadfence_block(); // fence E: Phase 1 visible
            // --- Phase 2: rep lanes vs strictly-later cycles ---
            int rp0 = onc0 && (n0 == cid0);
            int rp1 = onc1 && (n1 == cid1);
            unsigned long long q0 = __ballot(rp0);
            unsigned long long q1 = __ballot(rp1);
            int ncyc = (int)__popcll(q0) + (int)__popcll(q1);
            if (ncyc >= 2) {
                float inw0 = -INFINITY, outw0 = -INFINITY;
                float inw1 = -INFINITY, outw1 = -INFINITY;
                int qi0 = 0, qo0 = 0, qi1 = 0, qo1 = 0;
                int cidC = Lcid[0], mC = Lnode[0];
                float sbC = Lsub[0];
                for (int i = 0; i < Mtot; ++i) {
                    int cidN = 0, mN = 0; float sbN = 0.0f;
                    if (i + 1 < Mtot) { cidN = Lcid[i + 1]; mN = Lnode[i + 1]; sbN = Lsub[i + 1]; }
                    int e0 = rp0 && (cidC > cid0);
                    int e1 = rp1 && (cidC > cid1);
                    if (e0) {
                        float si = score[mC * 129 + n0];
                        float so = score[n0 * 129 + mC] - sbC;
                        int wi = oio[mC * 129 + n0];
                        int wo = oio[n0 * 129 + mC];
                        if (si > inw0) { inw0 = si; qi0 = wi; }
                        if (so > outw0) { outw0 = so; qo0 = wo; }
                    }
                    if (e1) {
                        float si = score[mC * 129 + n1];
                        float so = score[n1 * 129 + mC] - sbC;
                        int wi = oio[mC * 129 + n1];
                        int wo = oio[n1 * 129 + mC];
                        if (si > inw1) { inw1 = si; qi1 = wi; }
                        if (so > outw1) { outw1 = so; qo1 = wo; }
                    }
                    int segend = (i + 1 == Mtot) || (cidN != cidC);
                    if (segend) {
                        if (e0) {
                            float cwc = cwacc[cidC];
                            score[cidC * 129 + n0] = inw0; oio[cidC * 129 + n0] = (unsigned short)qi0;
                            score[n0 * 129 + cidC] = cwc + outw0; oio[n0 * 129 + cidC] = (unsigned short)qo0;
                        }
                        if (e1) {
                            float cwc = cwacc[cidC];
                            score[cidC * 129 + n1] = inw1; oio[cidC * 129 + n1] = (unsigned short)qi1;
                            score[n1 * 129 + cidC] = cwc + outw1; oio[n1 * 129 + cidC] = (unsigned short)qo1;
                        }
                        inw0 = -INFINITY; outw0 = -INFINITY;
                        inw1 = -INFINITY; outw1 = -INFINITY;
                    }
                    cidC = cidN; mC = mN; sbC = sbN;
                }
                __threadfence_block(); // fence F: Phase 2 visible
            }
            // --- deactivate dying members; remap parents into reps ---
            if (onc0 && n0 != cid0) c0 = 0;
            if (onc1 && n1 != cid1) c1 = 0;
            if (c0 && n0 != 0) { int cp = cidarr[p0]; if (cp != 0xFF) p0 = cp; }
            if (c1)            { int cp = cidarr[p1]; if (cp != 0xFF) p1 = cp; }
            // --- surviving reps: column rescans, 2 butterflies interleaved ---
            {
                unsigned long long w0 = q0, w1 = q1;
                while (w0 | w1) {
                    int repA, repB = -1;
                    if (w0) { repA = (int)__ffsll((long long)w0) - 1; w0 &= w0 - 1; }
                    else    { repA = 64 + (int)__ffsll((long long)w1) - 1; w1 &= w1 - 1; }
                    if (w0) { repB = (int)__ffsll((long long)w0) - 1; w0 &= w0 - 1; }
                    else if (w1) { repB = 64 + (int)__ffsll((long long)w1) - 1; w1 &= w1 - 1; }
                    float aA = c0 ? score[n0 * 129 + repA] : -INFINITY;
                    float bA = c1 ? score[n1 * 129 + repA] : -INFINITY;
                    float aB = -INFINITY, bB = -INFINITY;
                    if (repB >= 0) {
                        aB = c0 ? score[n0 * 129 + repB] : -INFINITY;
                        bB = c1 ? score[n1 * 129 + repB] : -INFINITY;
                    }
                    float vA; int iA;
                    if (bA > aA) { vA = bA; iA = n1; } else { vA = aA; iA = n0; }
                    float vB; int iB;
                    if (bB > aB) { vB = bB; iB = n1; } else { vB = aB; iB = n0; }
#pragma unroll
                    for (int off = 32; off >= 1; off >>= 1) {
                        float oA = __shfl_xor(vA, off, 64);
                        int jA = __shfl_xor(iA, off, 64);
                        float oB = __shfl_xor(vB, off, 64);
                        int jB = __shfl_xor(iB, off, 64);
                        if (oA > vA || (oA == vA && jA < iA)) { vA = oA; iA = jA; }
                        if (oB > vB || (oB == vB && jB < iB)) { vB = oB; iB = jB; }
                    }
                    if (n0 == repA) p0 = iA;
                    if (n1 == repA) p1 = iA;
                    if (repB >= 0) {
                        if (n0 == repB) p0 = iB;
                        if (n1 == repB) p1 = iB;
                    }
                }
            }
            nact -= (Mtot - ncyc);
            ++lev;
        }
        // --- unwind: per-pass levels, disjoint parallel walks ---
        int ltop = lev < 96 ? lev : 96;
        for (int l2 = ltop - 1; l2 >= 0; --l2) {
            int ky0 = kynL[l2 * 128 + n0], ky1 = kynL[l2 * 128 + n1];
            int cand0 = (ky0 != 0xFF) && (fe[n0] != -2);
            int cand1 = (ky1 != 0xFF) && (fe[n1] != -2);
            if (cand0) {
                int key = ky0;
                int prev = pstL[l2 * 128 + key];
                int guard = 0;
                while (prev != key && guard++ < 130) {
                    int pp2 = pstL[l2 * 128 + prev];
                    int w = oio[pp2 * 129 + prev];
                    fe[w >> 8] = w & 255;
                    prev = pp2;
                }
            }
            if (cand1) {
                int key = ky1;
                int prev = pstL[l2 * 128 + key];
                int guard = 0;
                while (prev != key && guard++ < 130) {
                    int pp2 = pstL[l2 * 128 + prev];
                    int w = oio[pp2 * 129 + prev];
                    fe[w >> 8] = w & 255;
                    prev = pp2;
                }
            }
            __threadfence_block();
        }
    }
    __syncthreads(); // ---- barrier B: waves 1-3 rejoin ----

    // --- emit heads / head_type ---
    if (t < 128) {
        int f = fe[t];
        float h, ht;
        if (f != -2) {
            h = (float)f;
            int prow = (f < 0) ? 127 : f; // numpy negative-index semantics for root
            ht = (float)(int)labmax_g[(size_t)b * 16384 + prow * 128 + t];
        } else { h = 0.0f; ht = 1.0f; }
        heads[b * 128 + t] = h;
        tags[b * 128 + t] = ht;
    }
}

extern "C" void kernel_launch(void* const* d_in, const int* in_sizes, int n_in,
                              void* d_out, int out_size, void* d_ws, size_t ws_size,
                              hipStream_t stream)
{
    const float* X   = (const float*)d_in[0];
    const float* Wha = (const float*)d_in[1];
    const float* bha = (const float*)d_in[2];
    const float* Wda = (const float*)d_in[3];
    const float* bda = (const float*)d_in[4];
    const float* Ua  = (const float*)d_in[5];
    const float* Whl = (const float*)d_in[6];
    const float* bhl = (const float*)d_in[7];
    const float* Wdl = (const float*)d_in[8];
    const float* bdl = (const float*)d_in[9];
    const float* Ul  = (const float*)d_in[10];
    // d_in[11] = mask: all-ones in this problem; length = 128 per batch.

    char* ws = (char*)d_ws;
    float* HA    = (float*)(ws + (size_t)0);
    float* DA    = (float*)(ws + ((size_t)8 << 20));
    float* TA    = (float*)(ws + ((size_t)16 << 20));
    float* HL    = (float*)(ws + ((size_t)24 << 20));
    float* DL    = (float*)(ws + ((size_t)26 << 20));
    float* DLt   = (float*)(ws + ((size_t)28 << 20));
    float* ARC   = (float*)(ws + ((size_t)30 << 20));
    float* SCORE = (float*)(ws + ((size_t)32 << 20));                  // 2 MB
    unsigned char* LABMAX = (unsigned char*)(ws + ((size_t)34 << 20)); // 512 KB

    float* E     = (float*)d_out;
    float* heads = E + (size_t)B_ * L_ * T_ * T_;
    float* tags  = heads + (size_t)B_ * T_;

    dim3 thr(256);
    // fused projections + bias + ELU (one launch, 640 blocks)
    proj_gemm_k<<<dim3(10, 64), thr, 0, stream>>>(X, Wha, bha, Wda, bda, Whl, bhl, Wdl, bdl,
                                                  HA, DA, HL, DL);
    // TA = HA @ U_arc
    gemm_k<<<dim3(4, 64, 1), thr, 0, stream>>>(HA, Ua, nullptr, TA, 512, 512, 512, 512, 0, 0, 0, (long long)128 * 512, 0);
    // DLt[b][s][j]
    transpose_k<<<dim3(4, 4, 32), dim3(32, 8), 0, stream>>>(DL, DLt);
    // arc_scores[b] = TA_b @ DA_b^T
    gemm_k<<<dim3(1, 2, 32), thr, 0, stream>>>(TA, DA, nullptr, ARC, 512, 512, 512, 128, 65536, 65536, 16384, 0, 4);
    // log_softmax over i, in place
    arc_logsoftmax_k<<<32, 128, 0, stream>>>(ARC);
    // fused: E[b,l] = (HL_b @ U_lab[l]) @ DLt_b  (two gemm_k bodies per block)
    tl_lab_k<<<dim3(50, 32, 2), thr, 0, stream>>>(HL, Ul, DLt, E);
    // label log-softmax + combine with norm_arc + exp + fused score/argmax
    energy_combine_k<<<2048, 256, 0, stream>>>(E, ARC, SCORE, LABMAX);
    // MST decode (all cycles per pass, two-sweep sequential-equivalent)
    mst_k<<<32, 256, 0, stream>>>(SCORE, LABMAX, heads, tags);
}